// Round 8
// baseline (80.953 us; speedup 1.0000x reference)
//
#include <hip/hip_runtime.h>

#define N_ATOMS  4096
#define N_RBF    16
#define N_HIDDEN 64
#define NTHREADS 1024
#define WPB      16                 // waves per block
#define APB      16                 // atoms per block (4 per wave-team of 4)
#define NBLOCKS  (N_ATOMS / APB)    // 256 -> exactly 1 block per CU
#define QCAP     96                 // per (atom, quarter) queue; max observed ~60
#define QUART    (N_ATOMS / 4)      // 1024

// One pair's RBF contribution into f[0..15]. d2=1e8 sentinel -> exactly 0.
__device__ __forceinline__ void accum_rbf(float d2, float (&f)[N_RBF]) {
    const float d  = sqrtf(d2);
    const float sm = 0.5f + 0.5f * __cosf(0.62831853071795865f * d); // 0.5*(1+cos(pi*d/5))
    #pragma unroll
    for (int k = 0; k < N_RBF; ++k) {
        const float t = d - (0.5f + 0.3f * (float)k);   // centers 0.5+0.3k
        f[k] += sm * __expf(-20.48f * t * t);           // 1/(2*eta^2) = 20.48
    }
}

__device__ __forceinline__ int wave_prefix(unsigned long long m) {
    return __builtin_amdgcn_mbcnt_hi((unsigned)(m >> 32),
            __builtin_amdgcn_mbcnt_lo((unsigned)m, 0u));
}

__global__ __launch_bounds__(NTHREADS) void fused_sr_kernel(
    const float* __restrict__ pos,   // (N,3)
    const float* __restrict__ W1,    // (16,64)
    const float* __restrict__ b1,    // (64,)
    const float* __restrict__ W2,    // (64,64)
    const float* __restrict__ b2,    // (64,)
    const float* __restrict__ W3,    // (64,1)
    const float* __restrict__ b3,    // (1,)
    float* __restrict__ out,         // scalar
    float* __restrict__ wsf,         // NBLOCKS partials (workspace)
    unsigned* __restrict__ wscnt)    // completion counter (workspace, poison-init)
{
    __shared__ __align__(16) float4 sp[N_ATOMS];          // 64 KB
    __shared__ __align__(16) float  qd[APB][4][QCAP];     // 24 KB per-ATOM quarter queues
    __shared__ int qcnt[APB][4];
    __shared__ __align__(16) float  h1buf[WPB][N_HIDDEN]; // 4 KB
    __shared__ float ered[WPB];
    // ~92.4 KB -> 1 block/CU, 16 waves/CU (4/SIMD)

    const int tid = threadIdx.x;

    for (int idx = tid; idx < N_ATOMS; idx += NTHREADS) {
        sp[idx] = make_float4(pos[idx * 3 + 0], pos[idx * 3 + 1], pos[idx * 3 + 2], 0.0f);
    }
    __syncthreads();

    const int lane = tid & 63;
    const int w    = tid >> 6;
    const int t    = w >> 2;            // team of 4 waves
    const int q    = w & 3;             // j-quarter this wave sweeps
    const int iA   = blockIdx.x * APB + 4 * t;

    const float4 p0 = sp[iA + 0];
    const float4 p1 = sp[iA + 1];
    const float4 p2 = sp[iA + 2];
    const float4 p3 = sp[iA + 3];
    const int jbase = q * QUART;

    // ---- sweep this j-quarter for 4 atoms: one ds_read_b128 feeds 4 tests ----
    int c0_ = 0, c1_ = 0, c2_ = 0, c3_ = 0;

#define PAIR_TEST(P, CNT, AIDX)                                              \
    {                                                                        \
        const float dx = P.x - pj.x, dy = P.y - pj.y, dz = P.z - pj.z;       \
        const float d2 = fmaf(dx, dx, fmaf(dy, dy, dz * dz));                \
        const bool act = (d2 < 25.0f) && (d2 > 1e-12f);                      \
        const unsigned long long m = __ballot(act);                          \
        if (m) { /* wave-uniform skip: s_cbranch when no lane hit */         \
            int widx = CNT + wave_prefix(m);                                 \
            widx = widx < QCAP ? widx : QCAP - 1;                            \
            if (act) qd[4 * t + AIDX][q][widx] = d2;                         \
            CNT += (int)__popcll(m);                                         \
        }                                                                    \
    }

    #pragma unroll 4
    for (int j0 = 0; j0 < QUART; j0 += 64) {
        const float4 pj = sp[jbase + j0 + lane];
        PAIR_TEST(p0, c0_, 0)
        PAIR_TEST(p1, c1_, 1)
        PAIR_TEST(p2, c2_, 2)
        PAIR_TEST(p3, c3_, 3)
    }
#undef PAIR_TEST

    if (lane == 0) {
        qcnt[4 * t + 0][q] = c0_;
        qcnt[4 * t + 1][q] = c1_;
        qcnt[4 * t + 2][q] = c2_;
        qcnt[4 * t + 3][q] = c3_;
    }
    __syncthreads();
    // Handoff: wave w now EXCLUSIVELY owns atom slot w (all 4 of its quarter queues).

    const int co0 = qcnt[w][0], co1 = qcnt[w][1], co2 = qcnt[w][2], co3 = qcnt[w][3];
    const int o1 = co0, o2 = co0 + co1, o3 = o2 + co2, C = o3 + co3;
    float* qrow = &qd[w][0][0];   // wave-exclusive [4][QCAP] region

    // ---- packed drain: logical concat of 4 quarter queues, ~1 batch/atom ----
    float f[N_RBF];
    #pragma unroll
    for (int k = 0; k < N_RBF; ++k) f[k] = 0.0f;
    for (int b = 0; b < C; b += 64) {
        const int g = b + lane;
        const int part = (g >= o1) + (g >= o2) + (g >= o3);
        const int base = part == 0 ? 0 : (part == 1 ? o1 : (part == 2 ? o2 : o3));
        const float d2q = (g < C) ? qrow[part * QCAP + (g - base)] : 1e8f;
        accum_rbf(d2q, f);
    }

    // ---- allreduce of f[16]: 2 xor folds + LDS transpose finish (R7-verified) ----
    #pragma unroll
    for (int k = 0; k < N_RBF; ++k) {
        f[k] += __shfl_xor(f[k], 32, 64);
        f[k] += __shfl_xor(f[k], 16, 64);   // lane l: sum over lanes {l&15 + 16r}
    }
    float* tb = qrow;   // 384-float wave-exclusive scratch (queues dead)
    if (lane < 16) {
        #pragma unroll
        for (int j = 0; j < 16; j += 4)
            *reinterpret_cast<float4*>(&tb[lane * 16 + j]) =
                make_float4(f[j], f[j + 1], f[j + 2], f[j + 3]);
    }
    const int kk = lane & 15, rep = lane >> 4;
    float F = 0.0f;
    #pragma unroll
    for (int i = 0; i < 4; ++i) F += tb[(4 * rep + i) * 16 + kk];
    F += __shfl_xor(F, 16, 64);
    F += __shfl_xor(F, 32, 64);            // full sum for k=lane&15
    if (lane < 16) tb[256 + lane] = F;
    float Fb[N_RBF];
    #pragma unroll
    for (int j = 0; j < 16; j += 4) {
        const float4 v = *reinterpret_cast<const float4*>(&tb[256 + j]);
        Fb[j] = v.x; Fb[j + 1] = v.y; Fb[j + 2] = v.z; Fb[j + 3] = v.w;
    }

    // ---- MLP for this wave's atom: lane <-> hidden unit ----
    float a1 = b1[lane];
    #pragma unroll
    for (int k = 0; k < N_RBF; ++k)
        a1 = fmaf(Fb[k], W1[k * N_HIDDEN + lane], a1);
    const float h1 = a1 / (1.0f + __expf(-a1));   // silu

    h1buf[w][lane] = h1;   // same-wave LDS exchange
    float a2 = b2[lane];
    #pragma unroll
    for (int k = 0; k < N_HIDDEN; k += 4) {
        const float4 hv = *reinterpret_cast<const float4*>(&h1buf[w][k]);
        a2 = fmaf(hv.x, W2[(k + 0) * N_HIDDEN + lane], a2);
        a2 = fmaf(hv.y, W2[(k + 1) * N_HIDDEN + lane], a2);
        a2 = fmaf(hv.z, W2[(k + 2) * N_HIDDEN + lane], a2);
        a2 = fmaf(hv.w, W2[(k + 3) * N_HIDDEN + lane], a2);
    }
    const float h2 = a2 / (1.0f + __expf(-a2));   // silu

    float e = h2 * W3[lane];
    #pragma unroll
    for (int off = 32; off > 0; off >>= 1)
        e += __shfl_xor(e, off, 64);
    if (lane == 0) ered[w] = e;
    __syncthreads();

    // ---- block partial -> ws; last block (poison-aware) reduces and stores out ----
    if (w == 0) {
        float acc = (lane < WPB) ? ered[lane] : 0.0f;
        acc += __shfl_xor(acc, 8, 64);
        acc += __shfl_xor(acc, 4, 64);
        acc += __shfl_xor(acc, 2, 64);
        acc += __shfl_xor(acc, 1, 64);     // lane 0: block sum
        int last = 0;
        if (lane == 0) {
            wsf[blockIdx.x] = acc + (float)APB * b3[0];
            __threadfence();
            const unsigned old = atomicAdd(wscnt, 1u);
            // ws is re-poisoned to 0xAA before every launch; accept 0-init too.
            last = (old == NBLOCKS - 1u) || (old == 0xAAAAAAAAu + (NBLOCKS - 1u));
        }
        last = __shfl(last, 0);
        if (last) {
            __threadfence();   // acquire: invalidate local caches before reading partials
            float tot = wsf[lane] + wsf[lane + 64] + wsf[lane + 128] + wsf[lane + 192];
            #pragma unroll
            for (int off = 32; off > 0; off >>= 1)
                tot += __shfl_xor(tot, off, 64);
            if (lane == 0) out[0] = tot;
        }
    }
}

extern "C" void kernel_launch(void* const* d_in, const int* in_sizes, int n_in,
                              void* d_out, int out_size, void* d_ws, size_t ws_size,
                              hipStream_t stream) {
    const float* pos = (const float*)d_in[0];
    const float* W1  = (const float*)d_in[1];
    const float* b1  = (const float*)d_in[2];
    const float* W2  = (const float*)d_in[3];
    const float* b2  = (const float*)d_in[4];
    const float* W3  = (const float*)d_in[5];
    const float* b3  = (const float*)d_in[6];
    float* out = (float*)d_out;

    float*    wsf   = (float*)d_ws;                  // NBLOCKS partials
    unsigned* wscnt = (unsigned*)((char*)d_ws + NBLOCKS * sizeof(float));

    fused_sr_kernel<<<NBLOCKS, NTHREADS, 0, stream>>>(pos, W1, b1, W2, b2, W3, b3,
                                                      out, wsf, wscnt);
}

// Round 9
// 80.727 us; speedup vs baseline: 1.0028x; 1.0028x over previous
//
#include <hip/hip_runtime.h>

#define N_ATOMS  4096
#define N_RBF    16
#define N_HIDDEN 64
#define NTHREADS 512
#define WPB      8                  // waves per block
#define APB      8                  // atoms per block (4 per wave-team of 4)
#define NBLOCKS  (N_ATOMS / APB)    // 512 -> 2 blocks/CU, 16 waves/CU
#define QCAP     96                 // per (atom, quarter) queue; max observed ~60
#define QUART    (N_ATOMS / 4)      // 1024

// ---- node 1: repack float3 positions -> float4 in workspace ----
__global__ __launch_bounds__(256) void repack_kernel(const float* __restrict__ pos,
                                                     float4* __restrict__ pos4) {
    const int i = blockIdx.x * 256 + threadIdx.x;
    if (i < N_ATOMS)
        pos4[i] = make_float4(pos[i * 3 + 0], pos[i * 3 + 1], pos[i * 3 + 2], 0.0f);
}

// One pair's RBF contribution into f[0..15]. d2=1e8 sentinel -> exactly 0.
__device__ __forceinline__ void accum_rbf(float d2, float (&f)[N_RBF]) {
    const float d  = sqrtf(d2);
    const float sm = 0.5f + 0.5f * __cosf(0.62831853071795865f * d); // 0.5*(1+cos(pi*d/5))
    #pragma unroll
    for (int k = 0; k < N_RBF; ++k) {
        const float t = d - (0.5f + 0.3f * (float)k);   // centers 0.5+0.3k
        f[k] += sm * __expf(-20.48f * t * t);           // 1/(2*eta^2) = 20.48
    }
}

__device__ __forceinline__ int wave_prefix(unsigned long long m) {
    return __builtin_amdgcn_mbcnt_hi((unsigned)(m >> 32),
            __builtin_amdgcn_mbcnt_lo((unsigned)m, 0u));
}

// ---- node 2: features + MLP, one atom per wave; sweep straight from L2 ----
__global__ __launch_bounds__(NTHREADS) void fused_sr_kernel(
    const float4* __restrict__ pos4, // (N,) packed, in ws (L2-resident, 64 KB)
    const float* __restrict__ W1,    // (16,64)
    const float* __restrict__ b1,    // (64,)
    const float* __restrict__ W2,    // (64,64)
    const float* __restrict__ b2,    // (64,)
    const float* __restrict__ W3,    // (64,1)
    float* __restrict__ partial)     // NBLOCKS block partials (in ws)
{
    __shared__ __align__(16) float qd[APB][4][QCAP];      // 12 KB per-atom quarter queues
    __shared__ int qcnt[APB][4];
    __shared__ __align__(16) float h1buf[WPB][N_HIDDEN];  // 2 KB
    __shared__ float ered[WPB];
    // ~14.5 KB -> LDS is no longer the occupancy limit (VGPR-capped 4 waves/SIMD)

    const int tid  = threadIdx.x;
    const int lane = tid & 63;
    const int w    = tid >> 6;
    const int t    = w >> 2;            // team of 4 waves
    const int q    = w & 3;             // j-quarter this wave sweeps
    const int iA   = blockIdx.x * APB + 4 * t;

    const float4 p0 = pos4[iA + 0];     // wave-uniform (L2 hit)
    const float4 p1 = pos4[iA + 1];
    const float4 p2 = pos4[iA + 2];
    const float4 p3 = pos4[iA + 3];
    const int jbase = q * QUART;

    // ---- sweep this j-quarter for 4 atoms: one global dwordx4 feeds 4 tests ----
    int c0_ = 0, c1_ = 0, c2_ = 0, c3_ = 0;

#define PAIR_TEST(P, CNT, AIDX)                                              \
    {                                                                        \
        const float dx = P.x - pj.x, dy = P.y - pj.y, dz = P.z - pj.z;       \
        const float d2 = fmaf(dx, dx, fmaf(dy, dy, dz * dz));                \
        const bool act = (d2 < 25.0f) && (d2 > 1e-12f);                      \
        const unsigned long long m = __ballot(act);                          \
        if (m) {                                                             \
            int widx = CNT + wave_prefix(m);                                 \
            widx = widx < QCAP ? widx : QCAP - 1;                            \
            if (act) qd[4 * t + AIDX][q][widx] = d2;                         \
            CNT += (int)__popcll(m);                                         \
        }                                                                    \
    }

    #pragma unroll 4
    for (int j0 = 0; j0 < QUART; j0 += 64) {
        const float4 pj = pos4[jbase + j0 + lane];   // coalesced, L2-resident
        PAIR_TEST(p0, c0_, 0)
        PAIR_TEST(p1, c1_, 1)
        PAIR_TEST(p2, c2_, 2)
        PAIR_TEST(p3, c3_, 3)
    }
#undef PAIR_TEST

    if (lane == 0) {
        qcnt[4 * t + 0][q] = c0_;
        qcnt[4 * t + 1][q] = c1_;
        qcnt[4 * t + 2][q] = c2_;
        qcnt[4 * t + 3][q] = c3_;
    }
    __syncthreads();
    // Handoff: wave w now exclusively owns atom slot w (its 4 quarter queues).

    const int co0 = qcnt[w][0], co1 = qcnt[w][1], co2 = qcnt[w][2], co3 = qcnt[w][3];
    const int o1 = co0, o2 = co0 + co1, o3 = o2 + co2, C = o3 + co3;
    float* qrow = &qd[w][0][0];   // wave-exclusive [4][QCAP] region

    // ---- packed drain: logical concat of 4 quarter queues, ~1 batch/atom ----
    float f[N_RBF];
    #pragma unroll
    for (int k = 0; k < N_RBF; ++k) f[k] = 0.0f;
    for (int b = 0; b < C; b += 64) {
        const int g = b + lane;
        const int part = (g >= o1) + (g >= o2) + (g >= o3);
        const int base = part == 0 ? 0 : (part == 1 ? o1 : (part == 2 ? o2 : o3));
        const float d2q = (g < C) ? qrow[part * QCAP + (g - base)] : 1e8f;
        accum_rbf(d2q, f);
    }

    // ---- allreduce of f[16]: 2 xor folds + LDS transpose finish ----
    #pragma unroll
    for (int k = 0; k < N_RBF; ++k) {
        f[k] += __shfl_xor(f[k], 32, 64);
        f[k] += __shfl_xor(f[k], 16, 64);   // lane l: sum over lanes {l&15 + 16r}
    }
    float* tb = qrow;   // 384-float wave-exclusive scratch (queues dead)
    if (lane < 16) {
        #pragma unroll
        for (int j = 0; j < 16; j += 4)
            *reinterpret_cast<float4*>(&tb[lane * 16 + j]) =
                make_float4(f[j], f[j + 1], f[j + 2], f[j + 3]);
    }
    const int kk = lane & 15, rep = lane >> 4;
    float F = 0.0f;
    #pragma unroll
    for (int i = 0; i < 4; ++i) F += tb[(4 * rep + i) * 16 + kk];
    F += __shfl_xor(F, 16, 64);
    F += __shfl_xor(F, 32, 64);            // full sum for k=lane&15
    if (lane < 16) tb[256 + lane] = F;
    float Fb[N_RBF];
    #pragma unroll
    for (int j = 0; j < 16; j += 4) {
        const float4 v = *reinterpret_cast<const float4*>(&tb[256 + j]);
        Fb[j] = v.x; Fb[j + 1] = v.y; Fb[j + 2] = v.z; Fb[j + 3] = v.w;
    }

    // ---- MLP for this wave's atom: lane <-> hidden unit ----
    float a1 = b1[lane];
    #pragma unroll
    for (int k = 0; k < N_RBF; ++k)
        a1 = fmaf(Fb[k], W1[k * N_HIDDEN + lane], a1);
    const float h1 = a1 / (1.0f + __expf(-a1));   // silu

    h1buf[w][lane] = h1;   // same-wave LDS exchange (DS in-order)
    float a2 = b2[lane];
    #pragma unroll
    for (int k = 0; k < N_HIDDEN; k += 4) {
        const float4 hv = *reinterpret_cast<const float4*>(&h1buf[w][k]);
        a2 = fmaf(hv.x, W2[(k + 0) * N_HIDDEN + lane], a2);
        a2 = fmaf(hv.y, W2[(k + 1) * N_HIDDEN + lane], a2);
        a2 = fmaf(hv.z, W2[(k + 2) * N_HIDDEN + lane], a2);
        a2 = fmaf(hv.w, W2[(k + 3) * N_HIDDEN + lane], a2);
    }
    const float h2 = a2 / (1.0f + __expf(-a2));   // silu

    float e = h2 * W3[lane];
    #pragma unroll
    for (int off = 32; off > 0; off >>= 1)
        e += __shfl_xor(e, off, 64);
    if (lane == 0) ered[w] = e;
    __syncthreads();

    if (tid < 64) {   // first wave: reduce 8 wave partials, store block partial
        float acc = (lane < WPB) ? ered[lane] : 0.0f;
        acc += __shfl_xor(acc, 4, 64);
        acc += __shfl_xor(acc, 2, 64);
        acc += __shfl_xor(acc, 1, 64);
        if (lane == 0) partial[blockIdx.x] = acc;
    }
}

// ---- node 3: reduce NBLOCKS partials -> out ----
__global__ __launch_bounds__(NTHREADS) void finish_kernel(
    const float* __restrict__ partial, const float* __restrict__ b3,
    float* __restrict__ out) {
    __shared__ float s[WPB];
    const int tid = threadIdx.x, lane = tid & 63, w = tid >> 6;
    float v = partial[tid];
    #pragma unroll
    for (int off = 32; off > 0; off >>= 1)
        v += __shfl_xor(v, off, 64);
    if (lane == 0) s[w] = v;
    __syncthreads();
    if (tid == 0) {
        float tot = 0.0f;
        #pragma unroll
        for (int i = 0; i < WPB; ++i) tot += s[i];
        out[0] = tot + (float)N_ATOMS * b3[0];
    }
}

extern "C" void kernel_launch(void* const* d_in, const int* in_sizes, int n_in,
                              void* d_out, int out_size, void* d_ws, size_t ws_size,
                              hipStream_t stream) {
    const float* pos = (const float*)d_in[0];
    const float* W1  = (const float*)d_in[1];
    const float* b1  = (const float*)d_in[2];
    const float* W2  = (const float*)d_in[3];
    const float* b2  = (const float*)d_in[4];
    const float* W3  = (const float*)d_in[5];
    const float* b3  = (const float*)d_in[6];
    float* out = (float*)d_out;

    float4* pos4    = (float4*)d_ws;                             // 64 KB
    float*  partial = (float*)((char*)d_ws + N_ATOMS * sizeof(float4));

    repack_kernel<<<(N_ATOMS + 255) / 256, 256, 0, stream>>>(pos, pos4);
    fused_sr_kernel<<<NBLOCKS, NTHREADS, 0, stream>>>(pos4, W1, b1, W2, b2, W3, partial);
    finish_kernel<<<1, NTHREADS, 0, stream>>>(partial, b3, out);
}